// Round 6
// baseline (67.579 us; speedup 1.0000x reference)
//
#include <hip/hip_runtime.h>
#include <math.h>

#define CH   64
#define NTOT 4096
#define NB   4

typedef short  short4v  __attribute__((ext_vector_type(4)));
typedef short  short8v  __attribute__((ext_vector_type(8)));
typedef float  floatx4  __attribute__((ext_vector_type(4)));

static __device__ __forceinline__ short f2bf(float f) {
    union { float f; unsigned int u; } v; v.f = f;
    unsigned int r = v.u + 0x7FFFu + ((v.u >> 16) & 1u);   // RNE
    return (short)(r >> 16);
}

// ---------------------------------------------------------------------------
// Kernel 1: QKV projection (fp32 compute) -> bf16 outputs
//   kT, qT : (B, N, C)  bf16   (pos-major, for MFMA fragment reads)
//   v      : (B, C, N)  bf16
// ---------------------------------------------------------------------------
__global__ __launch_bounds__(256) void qkv_proj(
    const float* __restrict__ x,
    const float* __restrict__ Wk, const float* __restrict__ Wq,
    const float* __restrict__ Wv,
    short* __restrict__ kT, short* __restrict__ qT, short* __restrict__ vg)
{
    __shared__ __align__(16) float xs [64][68];
    __shared__ __align__(16) float wkT[64][68];
    __shared__ __align__(16) float wqT[64][68];
    __shared__ __align__(16) float wvT[64][68];

    const int tid = threadIdx.x;
    const int b  = blockIdx.x >> 6;
    const int n0 = (blockIdx.x & 63) * 64;
    const float* xb = x + (size_t)b * CH * NTOT;

    for (int i = tid; i < 64 * 64; i += 256) {
        int c = i >> 6, n = i & 63;
        xs[c][n] = xb[(size_t)c * NTOT + n0 + n];
    }
    for (int i = tid; i < 64 * 64; i += 256) {
        int o = i >> 6, c = i & 63;
        wkT[c][o] = Wk[i];
        wqT[c][o] = Wq[i];
        wvT[c][o] = Wv[i];
    }
    __syncthreads();

    const int to = tid >> 4, tn = tid & 15;
    const int ob = to * 4, nb = tn * 4;
    float ak[4][4] = {}, aq[4][4] = {}, av[4][4] = {};

    for (int c = 0; c < 64; ++c) {
        float4 xv = *(const float4*)&xs [c][nb];
        float4 k4 = *(const float4*)&wkT[c][ob];
        float4 q4 = *(const float4*)&wqT[c][ob];
        float4 v4 = *(const float4*)&wvT[c][ob];
        float xa[4] = {xv.x, xv.y, xv.z, xv.w};
        float ka[4] = {k4.x, k4.y, k4.z, k4.w};
        float qa[4] = {q4.x, q4.y, q4.z, q4.w};
        float va[4] = {v4.x, v4.y, v4.z, v4.w};
        #pragma unroll
        for (int i = 0; i < 4; ++i)
            #pragma unroll
            for (int j = 0; j < 4; ++j) {
                ak[i][j] += ka[i] * xa[j];
                aq[i][j] += qa[i] * xa[j];
                av[i][j] += va[i] * xa[j];
            }
    }

    #pragma unroll
    for (int j = 0; j < 4; ++j) {
        size_t row = (size_t)(b << 12) + n0 + nb + j;
        short4v kk = { f2bf(ak[0][j]), f2bf(ak[1][j]), f2bf(ak[2][j]), f2bf(ak[3][j]) };
        short4v qq = { f2bf(aq[0][j]), f2bf(aq[1][j]), f2bf(aq[2][j]), f2bf(aq[3][j]) };
        *(short4v*)&kT[row * 64 + ob] = kk;
        *(short4v*)&qT[row * 64 + ob] = qq;
    }
    #pragma unroll
    for (int i = 0; i < 4; ++i) {
        short4v vv = { f2bf(av[i][0]), f2bf(av[i][1]), f2bf(av[i][2]), f2bf(av[i][3]) };
        *(short4v*)&vg[(((size_t)(b << 6) + ob + i) << 12) + n0 + nb] = vv;
    }
}

// ---------------------------------------------------------------------------
// Kernel 2: flash-attention partial over a 1024-key chunk.
// grid = 4 kc x 4 b x 64 qblk = 1024 blocks, 256 threads = 4 waves.
// Wave w owns queries n0+16w..n0+16w+15; all 4 waves share the key chunk.
// Writes: O_part[part][q][c] fp32 (unnormalized, scaled by exp(-m)),
//         ml_part[part][0..63]=m, [64..127]=l.   part = b<<8 | kc<<6 | qblk.
// LDS: kTs[4608] | qS[4608] | vS[4608] | Ps[4][1152]  = 36 KB
//      (qS+vS reused at the end as f32 [64][68] transpose buffer)
// ---------------------------------------------------------------------------
__global__ __launch_bounds__(256) void attn_partial(
    const short* __restrict__ kT, const short* __restrict__ qT,
    const short* __restrict__ vg,
    float* __restrict__ opart, float* __restrict__ mlpart)
{
    __shared__ __align__(16) short smem[18432];   // 36864 B

    const int tid = threadIdx.x;
    const int w  = tid >> 6;
    const int l  = tid & 63;
    const int g  = l >> 4;
    const int ln = l & 15;

    // XCD swizzle: all 64 qblks of one (b,kc) land on one XCD (K/V L2-resident)
    const int bid  = blockIdx.x;
    const int xcd  = bid & 7, grp = bid >> 3;
    const int bk   = (xcd << 1) | (grp >> 6);    // 0..15 = (b,kc)
    const int b    = bk >> 2;
    const int kc   = bk & 3;
    const int qblk = grp & 63;
    const int n0   = qblk << 6;
    const int part = (b << 8) | (kc << 6) | qblk;
    const int kbase = kc << 10;

    const short* kTb = kT + ((size_t)(b << 12) + n0) * 64;
    const short* qTb = qT + ((size_t)b << 12) * 64;
    const short* vb  = vg + ((size_t)(b << 6) << 12);

    short* const kTs = smem;
    short* const qS  = smem + 4608;
    short* const vS  = smem + 9216;
    short* const PsW = smem + 13824 + w * 1152;

    // stage this block's 64 queries
    {
        int r0 = tid >> 3, c8 = (tid & 7) << 3;
        *(short8v*)&kTs[r0 * 72 + c8]        = *(const short8v*)&kTb[r0 * 64 + c8];
        *(short8v*)&kTs[(r0 + 32) * 72 + c8] = *(const short8v*)&kTb[(r0 + 32) * 64 + c8];
    }
    __syncthreads();

    // queries as B-fragment: B[k=c][col=ln] = kTs[(w<<4)+ln][c]
    short8v bS0 = *(const short8v*)&kTs[((w << 4) + ln) * 72 + (g << 3)];
    short8v bS1 = *(const short8v*)&kTs[((w << 4) + ln) * 72 + 32 + (g << 3)];

    float mrun = -1e30f;
    float lrun = 0.f;
    floatx4 acc_o[4];
    #pragma unroll
    for (int ct = 0; ct < 4; ++ct) acc_o[ct] = (floatx4){0.f, 0.f, 0.f, 0.f};

    const int i0 = tid, i1 = tid + 256;

    short8v pf[4];
    pf[0] = *(const short8v*)&qTb[(size_t)(kbase + (i0 >> 3)) * 64 + ((i0 & 7) << 3)];
    pf[1] = *(const short8v*)&qTb[(size_t)(kbase + (i1 >> 3)) * 64 + ((i1 & 7) << 3)];
    pf[2] = *(const short8v*)&vb[(size_t)(i0 >> 3) * 4096 + kbase + ((i0 & 7) << 3)];
    pf[3] = *(const short8v*)&vb[(size_t)(i1 >> 3) * 4096 + kbase + ((i1 & 7) << 3)];

    for (int t = 0; t < 16; ++t) {
        __syncthreads();                       // previous tile's readers done
        *(short8v*)&qS[(i0 >> 3) * 72 + ((i0 & 7) << 3)] = pf[0];
        *(short8v*)&qS[(i1 >> 3) * 72 + ((i1 & 7) << 3)] = pf[1];
        *(short8v*)&vS[(i0 >> 3) * 72 + ((i0 & 7) << 3)] = pf[2];
        *(short8v*)&vS[(i1 >> 3) * 72 + ((i1 & 7) << 3)] = pf[3];
        __syncthreads();                       // tile ready
        if (t < 15) {
            int m1 = kbase + ((t + 1) << 6);
            pf[0] = *(const short8v*)&qTb[(size_t)(m1 + (i0 >> 3)) * 64 + ((i0 & 7) << 3)];
            pf[1] = *(const short8v*)&qTb[(size_t)(m1 + (i1 >> 3)) * 64 + ((i1 & 7) << 3)];
            pf[2] = *(const short8v*)&vb[(size_t)(i0 >> 3) * 4096 + m1 + ((i0 & 7) << 3)];
            pf[3] = *(const short8v*)&vb[(size_t)(i1 >> 3) * 4096 + m1 + ((i1 & 7) << 3)];
        }

        // ---- S^T tile: A = keys (qS rows), B = queries ----
        floatx4 sacc[4];
        #pragma unroll
        for (int mt = 0; mt < 4; ++mt) {
            short8v a0 = *(const short8v*)&qS[((mt << 4) + ln) * 72 + (g << 3)];
            short8v a1 = *(const short8v*)&qS[((mt << 4) + ln) * 72 + 32 + (g << 3)];
            floatx4 acc = (floatx4){0.f, 0.f, 0.f, 0.f};
            acc = __builtin_amdgcn_mfma_f32_16x16x32_bf16(a0, bS0, acc, 0, 0, 0);
            acc = __builtin_amdgcn_mfma_f32_16x16x32_bf16(a1, bS1, acc, 0, 0, 0);
            sacc[mt] = acc;
        }

        // ---- online softmax: 16 m-values for query ln in-lane + 2 shfl ----
        float mx = sacc[0][0];
        #pragma unroll
        for (int mt = 0; mt < 4; ++mt)
            #pragma unroll
            for (int r = 0; r < 4; ++r) mx = fmaxf(mx, sacc[mt][r]);
        mx = fmaxf(mx, __shfl_xor(mx, 16));
        mx = fmaxf(mx, __shfl_xor(mx, 32));

        float mnew = fmaxf(mrun, mx);
        float fs = __expf(mrun - mnew);
        mrun = mnew;

        float s = 0.f;
        #pragma unroll
        for (int mt = 0; mt < 4; ++mt) {
            float p0 = __expf(sacc[mt][0] - mnew);
            float p1 = __expf(sacc[mt][1] - mnew);
            float p2 = __expf(sacc[mt][2] - mnew);
            float p3 = __expf(sacc[mt][3] - mnew);
            s += (p0 + p1) + (p2 + p3);
            short4v p4 = { f2bf(p0), f2bf(p1), f2bf(p2), f2bf(p3) };
            *(short4v*)&PsW[ln * 72 + (mt << 4) + (g << 2)] = p4;
        }
        s += __shfl_xor(s, 16);
        s += __shfl_xor(s, 32);
        lrun = lrun * fs + s;

        #pragma unroll
        for (int ct = 0; ct < 4; ++ct) {
            acc_o[ct][0] *= fs; acc_o[ct][1] *= fs;
            acc_o[ct][2] *= fs; acc_o[ct][3] *= fs;
        }

        // ---- PV: D[c][n] += v[c][m] * P[m][n]  (intra-wave LDS dep) ----
        short8v bp0 = *(const short8v*)&PsW[ln * 72 + (g << 3)];
        short8v bp1 = *(const short8v*)&PsW[ln * 72 + 32 + (g << 3)];
        #pragma unroll
        for (int ct = 0; ct < 4; ++ct) {
            short8v a0 = *(const short8v*)&vS[((ct << 4) + ln) * 72 + (g << 3)];
            short8v a1 = *(const short8v*)&vS[((ct << 4) + ln) * 72 + 32 + (g << 3)];
            acc_o[ct] = __builtin_amdgcn_mfma_f32_16x16x32_bf16(a0, bp0, acc_o[ct], 0, 0, 0);
            acc_o[ct] = __builtin_amdgcn_mfma_f32_16x16x32_bf16(a1, bp1, acc_o[ct], 0, 0, 0);
        }
    }

    // ---- emit partial: transpose through LDS for coalesced fp32 store ----
    __syncthreads();                           // done reading qS/vS
    float* xp = (float*)(smem + 4608);         // [64 q][68 c]
    #pragma unroll
    for (int ct = 0; ct < 4; ++ct)
        #pragma unroll
        for (int r = 0; r < 4; ++r)
            xp[((w << 4) + ln) * 68 + (ct << 4) + (g << 2) + r] = acc_o[ct][r];
    if (g == 0) {
        mlpart[(size_t)part * 128 + (w << 4) + ln]      = mrun;
        mlpart[(size_t)part * 128 + 64 + (w << 4) + ln] = lrun;
    }
    __syncthreads();
    {
        int q = tid >> 2, c16 = (tid & 3) << 4;
        float* Ob = opart + (size_t)part * 4096 + q * 64 + c16;
        #pragma unroll
        for (int i = 0; i < 4; ++i)
            *(float4*)&Ob[i << 2] = *(const float4*)&xp[q * 68 + c16 + (i << 2)];
    }
}

// ---------------------------------------------------------------------------
// Kernel 3: merge 4 key-chunk partials + W2 + BN + ReLU + residual.
// grid = 4 b x 64 qblk = 256 blocks, 256 threads = 4 waves.
// ---------------------------------------------------------------------------
__global__ __launch_bounds__(256) void attn_merge(
    const float* __restrict__ opart, const float* __restrict__ mlpart,
    const float* __restrict__ W2,
    const float* __restrict__ gamma, const float* __restrict__ beta,
    const float* __restrict__ rmean, const float* __restrict__ rvar,
    const float* __restrict__ x, float* __restrict__ out)
{
    __shared__ __align__(16) short attL[64 * 72];   // bf16 att [q][c]
    __shared__ __align__(16) short w2s [64 * 72];   // bf16 W2  [o][c]
    __shared__ float wgt[4][64];
    __shared__ float linv[64];

    const int tid = threadIdx.x;
    const int w  = tid >> 6;
    const int l  = tid & 63;
    const int g  = l >> 4;
    const int ln = l & 15;

    const int b    = blockIdx.x >> 6;
    const int qblk = blockIdx.x & 63;
    const int n0   = qblk << 6;
    const int part0 = (b << 8) | qblk;             // + (kc<<6)

    // per-query merge weights (threads 0..63) + stage W2 (all threads)
    if (tid < 64) {
        float m0 = mlpart[(size_t)(part0)        * 128 + tid];
        float m1 = mlpart[(size_t)(part0 + 64)   * 128 + tid];
        float m2 = mlpart[(size_t)(part0 + 128)  * 128 + tid];
        float m3 = mlpart[(size_t)(part0 + 192)  * 128 + tid];
        float l0 = mlpart[(size_t)(part0)        * 128 + 64 + tid];
        float l1 = mlpart[(size_t)(part0 + 64)   * 128 + 64 + tid];
        float l2 = mlpart[(size_t)(part0 + 128)  * 128 + 64 + tid];
        float l3 = mlpart[(size_t)(part0 + 192)  * 128 + 64 + tid];
        float mm = fmaxf(fmaxf(m0, m1), fmaxf(m2, m3));
        float w0 = __expf(m0 - mm), w1 = __expf(m1 - mm);
        float w2 = __expf(m2 - mm), w3 = __expf(m3 - mm);
        wgt[0][tid] = w0; wgt[1][tid] = w1; wgt[2][tid] = w2; wgt[3][tid] = w3;
        linv[tid] = 1.0f / (w0 * l0 + w1 * l1 + w2 * l2 + w3 * l3);
    }
    for (int i = tid; i < 1024; i += 256) {
        int r = i >> 4, c4 = (i & 15) << 2;
        float4 wv = *(const float4*)&W2[(r << 6) + c4];
        short4v s4 = { f2bf(wv.x), f2bf(wv.y), f2bf(wv.z), f2bf(wv.w) };
        *(short4v*)&w2s[r * 72 + c4] = s4;
    }
    __syncthreads();

    // weighted sum of partials -> att bf16 [q][c]
    {
        int q = tid >> 2, c16 = (tid & 3) << 4;
        float a[16] = {};
        #pragma unroll
        for (int kc = 0; kc < 4; ++kc) {
            float wk = wgt[kc][q];
            const float* Ob = opart + (size_t)(part0 + (kc << 6)) * 4096 + q * 64 + c16;
            #pragma unroll
            for (int i = 0; i < 4; ++i) {
                float4 o4 = *(const float4*)&Ob[i << 2];
                a[(i << 2) + 0] += wk * o4.x;
                a[(i << 2) + 1] += wk * o4.y;
                a[(i << 2) + 2] += wk * o4.z;
                a[(i << 2) + 3] += wk * o4.w;
            }
        }
        float li = linv[q];
        #pragma unroll
        for (int i = 0; i < 4; ++i) {
            short4v s4 = { f2bf(a[(i << 2) + 0] * li), f2bf(a[(i << 2) + 1] * li),
                           f2bf(a[(i << 2) + 2] * li), f2bf(a[(i << 2) + 3] * li) };
            *(short4v*)&attL[q * 72 + c16 + (i << 2)] = s4;
        }
    }
    __syncthreads();

    // y = W2 * att + BN + ReLU + residual; wave w = query group w, 4 o-tiles
    short8v bA0 = *(const short8v*)&attL[((w << 4) + ln) * 72 + (g << 3)];
    short8v bA1 = *(const short8v*)&attL[((w << 4) + ln) * 72 + 32 + (g << 3)];
    const int nq = n0 + (w << 4) + ln;
    #pragma unroll
    for (int ot = 0; ot < 4; ++ot) {
        short8v a0 = *(const short8v*)&w2s[((ot << 4) + ln) * 72 + (g << 3)];
        short8v a1 = *(const short8v*)&w2s[((ot << 4) + ln) * 72 + 32 + (g << 3)];
        floatx4 acc = (floatx4){0.f, 0.f, 0.f, 0.f};
        acc = __builtin_amdgcn_mfma_f32_16x16x32_bf16(a0, bA0, acc, 0, 0, 0);
        acc = __builtin_amdgcn_mfma_f32_16x16x32_bf16(a1, bA1, acc, 0, 0, 0);
        int o0 = (ot << 4) + (g << 2);
        float4 gm = *(const float4*)&gamma[o0];
        float4 bt = *(const float4*)&beta [o0];
        float4 rm = *(const float4*)&rmean[o0];
        float4 rv = *(const float4*)&rvar [o0];
        float gma[4] = {gm.x, gm.y, gm.z, gm.w};
        float bta[4] = {bt.x, bt.y, bt.z, bt.w};
        float rma[4] = {rm.x, rm.y, rm.z, rm.w};
        float rva[4] = {rv.x, rv.y, rv.z, rv.w};
        #pragma unroll
        for (int r = 0; r < 4; ++r) {
            float inv  = gma[r] * rsqrtf(rva[r] + 1e-5f);
            float bias = bta[r] - rma[r] * inv;
            size_t ga = (((size_t)(b << 6) + o0 + r) << 12) + nq;
            out[ga] = fmaxf(acc[r] * inv + bias, 0.f) + x[ga];
        }
    }
}

// ---------------------------------------------------------------------------
extern "C" void kernel_launch(void* const* d_in, const int* in_sizes, int n_in,
                              void* d_out, int out_size, void* d_ws, size_t ws_size,
                              hipStream_t stream)
{
    const float* x     = (const float*)d_in[0];
    const float* Wk    = (const float*)d_in[1];
    const float* Wq    = (const float*)d_in[2];
    const float* Wv    = (const float*)d_in[3];
    const float* W2    = (const float*)d_in[4];
    const float* gamma = (const float*)d_in[5];
    const float* beta  = (const float*)d_in[6];
    const float* rmean = (const float*)d_in[7];
    const float* rvar  = (const float*)d_in[8];
    float* out = (float*)d_out;

    const size_t plane = (size_t)NB * NTOT * CH;    // 1M elements
    short* kT = (short*)d_ws;
    short* qT = kT + plane;
    short* vv = qT + plane;
    float* opart  = (float*)(vv + plane);           // 1024 x 4096 f32 = 16 MB
    float* mlpart = opart + (size_t)1024 * 4096;    // 1024 x 128  f32 = 0.5 MB

    qkv_proj    <<<dim3(256),  dim3(256), 0, stream>>>(x, Wk, Wq, Wv, kT, qT, vv);
    attn_partial<<<dim3(1024), dim3(256), 0, stream>>>(kT, qT, vv, opart, mlpart);
    attn_merge  <<<dim3(256),  dim3(256), 0, stream>>>(opart, mlpart, W2, gamma, beta,
                                                       rmean, rvar, x, out);
}